// Round 4
// baseline (682.295 us; speedup 1.0000x reference)
//
#include <hip/hip_runtime.h>
#include <math.h>

// Problem constants
#define NB   256
#define TT   36
#define FF   50
#define PP   80
#define KK   161
#define NITER 100
#define LAMB 0.1f

#define CODE_SZ (NB*KK*FF)          // 2,060,800
#define D_OFF   CODE_SZ
#define R_OFF   (CODE_SZ + TT*KK)

// ws float layout:
// [1] = wn^2 accumulator (zeroed by k_build blk0, atomicAdd by phase-0 tail)
// [16..79] = ssq partials (64 blocks of k_build)
// [WSA1..] A1 image (D):   [Mt1:3][kt:6][h:2][512] f16 = 9216 floats
// [WSA2..] A2 image (D^T): [Mt2:6][kt:3][h:2][512] f16 = 9216 floats
#define WSA1 128
#define WSA2 (128 + 9216)

typedef _Float16 half8 __attribute__((ext_vector_type(8)));
typedef float f32x4  __attribute__((ext_vector_type(4)));
typedef float f32x16 __attribute__((ext_vector_type(16)));
#define MFMA_16(A,B,C) __builtin_amdgcn_mfma_f32_16x16x32_f16(A,B,C,0,0,0)
#define MFMA_32(A,B,C) __builtin_amdgcn_mfma_f32_32x32x16_f16(A,B,C,0,0,0)

// ---------------------------------------------------------------------------
// K1 (grid 64): build D (blk0 -> d_out), ssq partials -> ws[16+b],
// pack f16 hi/lo A-operand images for D (GEMM1, 16x16x32) and D^T (GEMM2,
// 32x32x16) into ws. All unscaled (Linv applied in k_fista).
__global__ __launch_bounds__(256) void k_build(const float* __restrict__ rr,
                                               const float* __restrict__ th,
                                               float* __restrict__ out,
                                               float* __restrict__ ws) {
    __shared__ float Dl[TT*KK];
    __shared__ float red[256];
    int tid = threadIdx.x, b = blockIdx.x;
    for (int e = tid; e < TT*KK; e += 256) {
        int t = e / KK, k = e % KK;
        float v;
        if (k == 0) v = 1.f;
        else if (k <= PP) { int p = k - 1;     v = powf(rr[p], (float)t) * cosf((float)t * th[p]); }
        else              { int p = k - 1 - PP; v = powf(rr[p], (float)t) * sinf((float)t * th[p]); }
        Dl[e] = v;
        if (b == 0) out[D_OFF + e] = v;
    }
    __syncthreads();
    float ssq = 0.f;
    for (int p = b*256 + tid; p < KK*KK; p += 64*256) {
        int k1 = p / KK, k2 = p % KK;
        float s = 0.f;
        for (int t = 0; t < TT; ++t) s += Dl[t*KK + k1] * Dl[t*KK + k2];
        ssq += s * s;
    }
    red[tid] = ssq;
    __syncthreads();
    for (int off = 128; off > 0; off >>= 1) {
        if (tid < off) red[tid] += red[tid + off];
        __syncthreads();
    }
    if (tid == 0) { ws[16 + b] = red[0]; if (b == 0) ws[1] = 0.f; }

    // A1: lane l holds A[m=l&15][k=8*(l>>4)+i] per 16x16x32 tile
    _Float16* a1 = (_Float16*)(ws + WSA1);
    for (int e = b*256 + tid; e < 3*6*2*512; e += 64*256) {
        int fp = e & 511, r = e >> 9;       // r = (Mt1*6+kt)*2 + h
        int h = r & 1, mk = r >> 1;
        int l = fp >> 3, i = fp & 7;
        int t = (mk / 6) * 16 + (l & 15);
        int j = (mk % 6) * 32 + ((l >> 4) << 3) + i;
        float v = (t < TT && j < KK) ? Dl[t*KK + j] : 0.f;
        _Float16 hi = (_Float16)v;
        a1[e] = h ? (_Float16)(v - (float)hi) : hi;
    }
    // A2 (D^T): lane l holds A[m=l&31][k=8*(l>>5)+i] per 32x32x16 tile
    _Float16* a2 = (_Float16*)(ws + WSA2);
    for (int e = b*256 + tid; e < 6*3*2*512; e += 64*256) {
        int fp = e & 511, r = e >> 9;       // r = (Mt2*3+kt)*2 + h
        int h = r & 1, mk = r >> 1;
        int l = fp >> 3, i = fp & 7;
        int m = (mk / 3) * 32 + (l & 31);               // atom index
        int t = (mk % 3) * 16 + ((l >> 5) << 3) + i;    // k-dim = time
        float v = (m < KK && t < TT) ? Dl[t*KK + m] : 0.f;
        _Float16 hi = (_Float16)v;
        a2[e] = h ? (_Float16)(v - (float)hi) : hi;
    }
}

// ---------------------------------------------------------------------------
// K2: fully fused FISTA. grid 512 (n = blk>>1, col-half = blk&1), 384 thr
// (6 waves), 2 blocks/CU. Head: DtY for own 32 cols via GEMM2 over x-tile.
// Peeled iter0 (Ay=0), 99-iter loop: z = D y (GEMM1 16x16x32, wave=(Mt1,nt1)),
// w = D^T z (GEMM2 32x32x16, wave=Mt2), f16 hi/lo split, fp32 accumulate.
// Tail ph0: store code + wn^2 atomicAdd. Tail ph1: store code + reconst.
__global__ __launch_bounds__(384, 3) void k_fista(float* __restrict__ ws,
                                                  const float* __restrict__ x,
                                                  float* __restrict__ out,
                                                  int phase) {
    __shared__ _Float16 Ys[2*2*6*512];   // 24,576 B: [h][nt16:2][kt32:6][512]
    __shared__ _Float16 Zs[2*3*512];     //  6,144 B: [h][kt16:3][512]
    int tid = threadIdx.x;
    int w = tid >> 6, l = tid & 63;
    int n = blockIdx.x >> 1, half = blockIdx.x & 1;

    // ---- head: x tile -> Zs split image (B-frag for GEMM2, k-dim = t)
    const float* xb = x + n*TT*FF + half*32;
    for (int e = tid; e < 1536; e += 384) {
        int k = e >> 5, c = e & 31;
        float v = 0.f;
        if (k < TT && half*32 + c < FF) v = xb[k*FF + c];
        _Float16 hi = (_Float16)v;
        int kt = k >> 4, kk = k & 15;
        int ofs = ((((kk >> 3) << 5) + c) << 3) + (kk & 7);
        Zs[((0*3 + kt) << 9) + ofs] = hi;
        Zs[((1*3 + kt) << 9) + ofs] = (_Float16)(v - (float)hi);
    }

    float ssum = 0.f;
    #pragma unroll
    for (int i = 0; i < 64; ++i) ssum += ws[16 + i];
    float linv = rsqrtf(ssum);

    int Mt1 = w >> 1, nt1 = w & 1;      // GEMM1 role
    int Mt2 = w;                        // GEMM2 role
    const _Float16* a1g = (const _Float16*)(ws + WSA1);
    const _Float16* a2g = (const _Float16*)(ws + WSA2);
    half8 a1[6][2], a2[3][2];
    #pragma unroll
    for (int kt = 0; kt < 6; ++kt)
        #pragma unroll
        for (int h = 0; h < 2; ++h)
            a1[kt][h] = *(const half8*)(a1g + ((((Mt1*6 + kt)*2 + h) << 9) + (l << 3)));
    #pragma unroll
    for (int kt = 0; kt < 3; ++kt)
        #pragma unroll
        for (int h = 0; h < 2; ++h)
            a2[kt][h] = *(const half8*)(a2g + ((((Mt2*3 + kt)*2 + h) << 9) + (l << 3)));
    __syncthreads();

    // ---- head GEMM2: acc = D^T @ Xtile  -> c-vector (in registers only)
    f32x16 acc;
    #pragma unroll
    for (int r = 0; r < 16; ++r) acc[r] = 0.f;
    #pragma unroll
    for (int kt = 0; kt < 3; ++kt) {
        half8 bh = *(const half8*)&Zs[((0*3 + kt) << 9) + (l << 3)];
        half8 bl = *(const half8*)&Zs[((1*3 + kt) << 9) + (l << 3)];
        acc = MFMA_32(a2[kt][0], bh, acc);
        acc = MFMA_32(a2[kt][0], bl, acc);
        acc = MFMA_32(a2[kt][1], bh, acc);
    }

    int cl = l & 15, q = l >> 4;        // GEMM1 C addressing
    int nloc = l & 31, s5 = l >> 5;     // GEMM2 C addressing
    int nt16 = nloc >> 4;
    int fcol = half*32 + nloc;          // global f for owned columns
    float cm[4][4], cp[4][4], xo[4][4], yo[4][4];
    {
        float wl0 = LAMB * linv;
        float fac = 0.f;
        if (phase) fac = (float)KK * LAMB * linv * rsqrtf(ws[1]);
        #pragma unroll
        for (int g = 0; g < 4; ++g) {
            int k0 = Mt2*32 + 8*g + 4*s5;
            union { unsigned long long u; _Float16 hh[4]; } yh, yl;
            #pragma unroll
            for (int j = 0; j < 4; ++j) {
                int k = k0 + j;
                float cv = 0.f, wl = 0.f;
                if (k < KK && fcol < FF) {
                    cv = linv * acc[g*4 + j];
                    if (phase) {
                        float prev = out[(size_t)n*KK*FF + k*FF + fcol];
                        wl = fac / (fabsf(prev) + 0.01f);
                    } else wl = wl0;
                }
                cm[g][j] = cv - wl; cp[g][j] = cv + wl;
                // peeled iteration 0: Ay = 0, beta = 0 -> y1 = x1
                float xn = fmaxf(0.f, cm[g][j]) + fminf(0.f, cp[g][j]);
                xo[g][j] = xn; yo[g][j] = xn;
                _Float16 hi = (_Float16)xn;
                yh.hh[j] = hi; yl.hh[j] = (_Float16)(xn - (float)hi);
            }
            int yofs = ((g*16 + cl) << 3) + (s5 << 2);
            *(unsigned long long*)&Ys[(((0*2 + nt16)*6 + Mt2) << 9) + yofs] = yh.u;
            *(unsigned long long*)&Ys[(((1*2 + nt16)*6 + Mt2) << 9) + yofs] = yl.u;
        }
    }
    int zofs = ((((q >> 1) << 5) + nt1*16 + cl) << 3) + ((q & 1) << 2);
    __syncthreads();   // y1 visible; all head Zs reads done

    float t_old = 0.5f * (1.f + sqrtf(5.f));
    for (int it = 1; it < NITER; ++it) {
        // ---- GEMM1: z(Mt1, nt1) = D @ y
        f32x4 za = {0.f,0.f,0.f,0.f}, zb = {0.f,0.f,0.f,0.f};
        #pragma unroll
        for (int kt = 0; kt < 6; ++kt) {
            half8 bh = *(const half8*)&Ys[(((0*2 + nt1)*6 + kt) << 9) + (l << 3)];
            half8 bl = *(const half8*)&Ys[(((1*2 + nt1)*6 + kt) << 9) + (l << 3)];
            if (kt & 1) { zb = MFMA_16(a1[kt][0], bh, zb); zb = MFMA_16(a1[kt][0], bl, zb); zb = MFMA_16(a1[kt][1], bh, zb); }
            else        { za = MFMA_16(a1[kt][0], bh, za); za = MFMA_16(a1[kt][0], bl, za); za = MFMA_16(a1[kt][1], bh, za); }
        }
        f32x4 zz = za + zb;
        {   // write z into GEMM2 B-frag image
            union { unsigned long long u; _Float16 hh[4]; } ph, pl;
            #pragma unroll
            for (int r = 0; r < 4; ++r) {
                float v = zz[r];
                _Float16 hi = (_Float16)v;
                ph.hh[r] = hi; pl.hh[r] = (_Float16)(v - (float)hi);
            }
            *(unsigned long long*)&Zs[((0*3 + Mt1) << 9) + zofs] = ph.u;
            *(unsigned long long*)&Zs[((1*3 + Mt1) << 9) + zofs] = pl.u;
        }
        __syncthreads();

        // ---- GEMM2: acc(Mt2) = D^T @ z
        #pragma unroll
        for (int r = 0; r < 16; ++r) acc[r] = 0.f;
        #pragma unroll
        for (int kt = 0; kt < 3; ++kt) {
            half8 bh = *(const half8*)&Zs[((0*3 + kt) << 9) + (l << 3)];
            half8 bl = *(const half8*)&Zs[((1*3 + kt) << 9) + (l << 3)];
            acc = MFMA_32(a2[kt][0], bh, acc);
            acc = MFMA_32(a2[kt][0], bl, acc);
            acc = MFMA_32(a2[kt][1], bh, acc);
        }
        // ---- epilogue: shrink + momentum, rebuild y image
        float t_new = 0.5f * (1.f + sqrtf(1.f + 4.f*t_old*t_old));
        float beta = (t_old - 1.f) / t_new;
        t_old = t_new;
        #pragma unroll
        for (int g = 0; g < 4; ++g) {
            union { unsigned long long u; _Float16 hh[4]; } yh, yl;
            #pragma unroll
            for (int j = 0; j < 4; ++j) {
                float ay = fmaf(-linv, acc[g*4 + j], yo[g][j]);
                float xn = fmaxf(0.f, ay + cm[g][j]) + fminf(0.f, ay + cp[g][j]);
                float yn = fmaf(beta, xn - xo[g][j], xn);
                xo[g][j] = xn; yo[g][j] = yn;
                _Float16 hi = (_Float16)yn;
                yh.hh[j] = hi; yl.hh[j] = (_Float16)(yn - (float)hi);
            }
            int yofs = ((g*16 + cl) << 3) + (s5 << 2);
            *(unsigned long long*)&Ys[(((0*2 + nt16)*6 + Mt2) << 9) + yofs] = yh.u;
            *(unsigned long long*)&Ys[(((1*2 + nt16)*6 + Mt2) << 9) + yofs] = yl.u;
        }
        __syncthreads();
    }

    // ---- store final code
    #pragma unroll
    for (int g = 0; g < 4; ++g) {
        int k0 = Mt2*32 + 8*g + 4*s5;
        #pragma unroll
        for (int j = 0; j < 4; ++j) {
            int k = k0 + j;
            if (k < KK && fcol < FF)
                out[(size_t)n*KK*FF + k*FF + fcol] = xo[g][j];
        }
    }

    if (!phase) {
        // ---- fused wnorm: sum 1/(|x|+0.01)^2 over valid elements
        float s = 0.f;
        #pragma unroll
        for (int g = 0; g < 4; ++g) {
            int k0 = Mt2*32 + 8*g + 4*s5;
            #pragma unroll
            for (int j = 0; j < 4; ++j) {
                if (k0 + j < KK && fcol < FF) {
                    float wn = 1.f / (fabsf(xo[g][j]) + 0.01f);
                    s += wn * wn;
                }
            }
        }
        #pragma unroll
        for (int off = 32; off > 0; off >>= 1) s += __shfl_down(s, off);
        float* red = (float*)Ys;   // safe: last loop barrier passed
        if (l == 0) red[w] = s;
        __syncthreads();
        if (tid == 0) {
            float t = red[0] + red[1] + red[2] + red[3] + red[4] + red[5];
            atomicAdd(&ws[1], t);
        }
    } else {
        // ---- fused reconst: write x into Ys image, GEMM1 pass, store
        #pragma unroll
        for (int g = 0; g < 4; ++g) {
            union { unsigned long long u; _Float16 hh[4]; } yh, yl;
            #pragma unroll
            for (int j = 0; j < 4; ++j) {
                float v = xo[g][j];
                _Float16 hi = (_Float16)v;
                yh.hh[j] = hi; yl.hh[j] = (_Float16)(v - (float)hi);
            }
            int yofs = ((g*16 + cl) << 3) + (s5 << 2);
            *(unsigned long long*)&Ys[(((0*2 + nt16)*6 + Mt2) << 9) + yofs] = yh.u;
            *(unsigned long long*)&Ys[(((1*2 + nt16)*6 + Mt2) << 9) + yofs] = yl.u;
        }
        __syncthreads();
        f32x4 za = {0.f,0.f,0.f,0.f}, zb = {0.f,0.f,0.f,0.f};
        #pragma unroll
        for (int kt = 0; kt < 6; ++kt) {
            half8 bh = *(const half8*)&Ys[(((0*2 + nt1)*6 + kt) << 9) + (l << 3)];
            half8 bl = *(const half8*)&Ys[(((1*2 + nt1)*6 + kt) << 9) + (l << 3)];
            if (kt & 1) { zb = MFMA_16(a1[kt][0], bh, zb); zb = MFMA_16(a1[kt][0], bl, zb); zb = MFMA_16(a1[kt][1], bh, zb); }
            else        { za = MFMA_16(a1[kt][0], bh, za); za = MFMA_16(a1[kt][0], bl, za); za = MFMA_16(a1[kt][1], bh, za); }
        }
        f32x4 zz = za + zb;
        int fcol2 = half*32 + nt1*16 + cl;
        #pragma unroll
        for (int r = 0; r < 4; ++r) {
            int t = Mt1*16 + q*4 + r;
            if (t < TT && fcol2 < FF)
                out[R_OFF + (size_t)n*TT*FF + t*FF + fcol2] = zz[r];
        }
    }
}

// ---------------------------------------------------------------------------
extern "C" void kernel_launch(void* const* d_in, const int* in_sizes, int n_in,
                              void* d_out, int out_size, void* d_ws, size_t ws_size,
                              hipStream_t stream) {
    const float* x  = (const float*)d_in[0];
    const float* rr = (const float*)d_in[1];
    const float* th = (const float*)d_in[2];
    float* out = (float*)d_out;
    float* ws  = (float*)d_ws;

    hipLaunchKernelGGL(k_build, dim3(64),  dim3(256), 0, stream, rr, th, out, ws);
    hipLaunchKernelGGL(k_fista, dim3(512), dim3(384), 0, stream, ws, x, out, 0);
    hipLaunchKernelGGL(k_fista, dim3(512), dim3(384), 0, stream, ws, x, out, 1);
}

// Round 5
// 635.873 us; speedup vs baseline: 1.0730x; 1.0730x over previous
//
#include <hip/hip_runtime.h>
#include <math.h>

// Problem constants
#define NB   256
#define TT   36
#define FF   50
#define PP   80
#define KK   161
#define NITER 100
#define LAMB 0.1f

#define CODE_SZ (NB*KK*FF)          // 2,060,800
#define D_OFF   CODE_SZ
#define R_OFF   (CODE_SZ + TT*KK)

// ws float layout:
// [1] = wn^2 accumulator; [16..79] = ssq partials (64 k_build blocks)
// [WSA1..] A1 image (D):   [Mt1:3][kt:6][h:2][512] f16 = 9216 floats
// [WSA2..] A2 image (D^T): [Mt2:6][kt:3][h:2][512] f16 = 9216 floats
#define WSA1 128
#define WSA2 (128 + 9216)

typedef _Float16 half8 __attribute__((ext_vector_type(8)));
typedef float f32x4  __attribute__((ext_vector_type(4)));
typedef float f32x16 __attribute__((ext_vector_type(16)));
#define MFMA_16(A,B,C) __builtin_amdgcn_mfma_f32_16x16x32_f16(A,B,C,0,0,0)
#define MFMA_32(A,B,C) __builtin_amdgcn_mfma_f32_32x32x16_f16(A,B,C,0,0,0)

// ---------------------------------------------------------------------------
// K1 (grid 64): build D (blk0 -> d_out), ssq partials -> ws[16+b], pack f16
// hi/lo MFMA A-operand images for D (GEMM1 16x16x32) and D^T (GEMM2 32x32x16).
__global__ __launch_bounds__(256) void k_build(const float* __restrict__ rr,
                                               const float* __restrict__ th,
                                               float* __restrict__ out,
                                               float* __restrict__ ws) {
    __shared__ float Dl[TT*KK];
    __shared__ float red[256];
    int tid = threadIdx.x, b = blockIdx.x;
    for (int e = tid; e < TT*KK; e += 256) {
        int t = e / KK, k = e % KK;
        float v;
        if (k == 0) v = 1.f;
        else if (k <= PP) { int p = k - 1;     v = powf(rr[p], (float)t) * cosf((float)t * th[p]); }
        else              { int p = k - 1 - PP; v = powf(rr[p], (float)t) * sinf((float)t * th[p]); }
        Dl[e] = v;
        if (b == 0) out[D_OFF + e] = v;
    }
    __syncthreads();
    float ssq = 0.f;
    for (int p = b*256 + tid; p < KK*KK; p += 64*256) {
        int k1 = p / KK, k2 = p % KK;
        float s = 0.f;
        for (int t = 0; t < TT; ++t) s += Dl[t*KK + k1] * Dl[t*KK + k2];
        ssq += s * s;
    }
    red[tid] = ssq;
    __syncthreads();
    for (int off = 128; off > 0; off >>= 1) {
        if (tid < off) red[tid] += red[tid + off];
        __syncthreads();
    }
    if (tid == 0) { ws[16 + b] = red[0]; if (b == 0) ws[1] = 0.f; }

    // A1: lane l holds A[m=l&15][k=8*(l>>4)+i] per 16x16x32 tile
    _Float16* a1 = (_Float16*)(ws + WSA1);
    for (int e = b*256 + tid; e < 3*6*2*512; e += 64*256) {
        int fp = e & 511, r = e >> 9;       // r = (Mt1*6+kt)*2 + h
        int h = r & 1, mk = r >> 1;
        int l = fp >> 3, i = fp & 7;
        int t = (mk / 6) * 16 + (l & 15);
        int j = (mk % 6) * 32 + ((l >> 4) << 3) + i;
        float v = (t < TT && j < KK) ? Dl[t*KK + j] : 0.f;
        _Float16 hi = (_Float16)v;
        a1[e] = h ? (_Float16)(v - (float)hi) : hi;
    }
    // A2 (D^T): lane l holds A[m=l&31][k=8*(l>>5)+i] per 32x32x16 tile
    _Float16* a2 = (_Float16*)(ws + WSA2);
    for (int e = b*256 + tid; e < 6*3*2*512; e += 64*256) {
        int fp = e & 511, r = e >> 9;       // r = (Mt2*3+kt)*2 + h
        int h = r & 1, mk = r >> 1;
        int l = fp >> 3, i = fp & 7;
        int m = (mk / 3) * 32 + (l & 31);
        int t = (mk % 3) * 16 + ((l >> 5) << 3) + i;
        float v = (m < KK && t < TT) ? Dl[t*KK + m] : 0.f;
        _Float16 hi = (_Float16)v;
        a2[e] = h ? (_Float16)(v - (float)hi) : hi;
    }
}

// ---------------------------------------------------------------------------
// K2: fused FISTA, grid 256 (one n per block), 768 threads = 12 waves =
// TWO independent 6-wave sub-problems (cols 0-31 / 32-63) running
// half-iteration out of phase: each half-step one sub does GEMM1 (z = D y,
// 16x16x32) while the other does GEMM2+epilogue (w = D^T z, 32x32x16).
// f16 hi/lo split, fp32 accumulate. Head: DtY via GEMM2 over x. Tails fused.
__global__ __launch_bounds__(768, 3) void k_fista(float* __restrict__ ws,
                                                  const float* __restrict__ x,
                                                  float* __restrict__ out,
                                                  int phase) {
    __shared__ _Float16 Ys[2*12288];   // per sub: [h:2][nt16:2][kt32:6][512]
    __shared__ _Float16 Zs[2*3072];    // per sub: [h:2][kt16:3][512]
    int tid = threadIdx.x;
    int w = tid >> 6, l = tid & 63;
    int p = (w >= 6) ? 1 : 0;          // sub-problem id
    int rg = w - 6*p;                  // role 0..5 within sub
    int n = blockIdx.x;
    _Float16* Ysp = Ys + p*12288;
    _Float16* Zsp = Zs + p*3072;

    // ---- stage x -> Zs[0], Zs[1] (GEMM2 B-frag images, k-dim = t)
    const float* xb = x + n*TT*FF;
    #pragma unroll
    for (int pp = 0; pp < 2; ++pp)
        for (int e = tid; e < 1536; e += 768) {
            int t = e >> 5, c = e & 31;
            int col = pp*32 + c;
            float v = (t < TT && col < FF) ? xb[t*FF + col] : 0.f;
            _Float16 hi = (_Float16)v;
            int kt = t >> 4, kk = t & 15;
            int ofs = ((((kk >> 3) << 5) + c) << 3) + (kk & 7);
            _Float16* Z = Zs + pp*3072;
            Z[((0*3 + kt) << 9) + ofs] = hi;
            Z[((1*3 + kt) << 9) + ofs] = (_Float16)(v - (float)hi);
        }

    float ssum = 0.f;
    #pragma unroll
    for (int i = 0; i < 64; ++i) ssum += ws[16 + i];
    float linv = rsqrtf(ssum);

    int Mt1 = rg >> 1, nt1 = rg & 1;   // GEMM1 role
    int Mt2 = rg;                      // GEMM2 role
    const _Float16* a1g = (const _Float16*)(ws + WSA1);
    const _Float16* a2g = (const _Float16*)(ws + WSA2);
    half8 a1[6][2], a2[3][2];
    #pragma unroll
    for (int kt = 0; kt < 6; ++kt)
        #pragma unroll
        for (int h = 0; h < 2; ++h)
            a1[kt][h] = *(const half8*)(a1g + ((((Mt1*6 + kt)*2 + h) << 9) + (l << 3)));
    #pragma unroll
    for (int kt = 0; kt < 3; ++kt)
        #pragma unroll
        for (int h = 0; h < 2; ++h)
            a2[kt][h] = *(const half8*)(a2g + ((((Mt2*3 + kt)*2 + h) << 9) + (l << 3)));
    __syncthreads();

    // ---- head GEMM2: acc = D^T @ Xtile (own sub's 32 cols)
    f32x16 acc;
    #pragma unroll
    for (int r = 0; r < 16; ++r) acc[r] = 0.f;
    #pragma unroll
    for (int kt = 0; kt < 3; ++kt) {
        half8 bh = *(const half8*)&Zsp[((0*3 + kt) << 9) + (l << 3)];
        half8 bl = *(const half8*)&Zsp[((1*3 + kt) << 9) + (l << 3)];
        acc = MFMA_32(a2[kt][0], bh, acc);
        acc = MFMA_32(a2[kt][0], bl, acc);
        acc = MFMA_32(a2[kt][1], bh, acc);
    }

    int cl = l & 15, q = l >> 4;       // GEMM1 C addressing
    int nloc = l & 31, s5 = l >> 5;    // GEMM2 C addressing
    int nt16 = nloc >> 4;
    int fcol = p*32 + nloc;            // global f of owned columns
    int zofs = ((((q >> 1) << 5) + nt1*16 + cl) << 3) + ((q & 1) << 2);
    float cm[4][4], cp[4][4], xo[4][4], yo[4][4];

    // ---- peeled iteration 0: x1 = shrink(c), y1 = x1
    {
        float wl0 = LAMB * linv;
        float fac = 0.f;
        if (phase) fac = (float)KK * LAMB * linv * rsqrtf(ws[1]);
        #pragma unroll
        for (int gq = 0; gq < 4; ++gq) {
            int k0 = Mt2*32 + 8*gq + 4*s5;
            union { unsigned long long u; _Float16 hh[4]; } yh, yl;
            #pragma unroll
            for (int j = 0; j < 4; ++j) {
                int k = k0 + j;
                float cv = 0.f, wl = 0.f;
                if (k < KK && fcol < FF) {
                    cv = linv * acc[gq*4 + j];
                    if (phase) {
                        float prev = out[(size_t)n*KK*FF + k*FF + fcol];
                        wl = fac / (fabsf(prev) + 0.01f);
                    } else wl = wl0;
                }
                cm[gq][j] = cv - wl; cp[gq][j] = cv + wl;
                float xn = fmaxf(0.f, cm[gq][j]) + fminf(0.f, cp[gq][j]);
                xo[gq][j] = xn; yo[gq][j] = xn;
                _Float16 hi = (_Float16)xn;
                yh.hh[j] = hi; yl.hh[j] = (_Float16)(xn - (float)hi);
            }
            int yofs = ((gq*16 + cl) << 3) + (s5 << 2);
            *(unsigned long long*)&Ysp[(((0*2 + nt16)*6 + Mt2) << 9) + yofs] = yh.u;
            *(unsigned long long*)&Ysp[(((1*2 + nt16)*6 + Mt2) << 9) + yofs] = yl.u;
        }
    }
    __syncthreads();

    // ---- role bodies
    auto G1body = [&]() {
        f32x4 za = {0.f,0.f,0.f,0.f}, zb = {0.f,0.f,0.f,0.f};
        #pragma unroll
        for (int kt = 0; kt < 6; ++kt) {
            half8 bh = *(const half8*)&Ysp[(((0*2 + nt1)*6 + kt) << 9) + (l << 3)];
            half8 bl = *(const half8*)&Ysp[(((1*2 + nt1)*6 + kt) << 9) + (l << 3)];
            if (kt & 1) { zb = MFMA_16(a1[kt][0], bh, zb); zb = MFMA_16(a1[kt][0], bl, zb); zb = MFMA_16(a1[kt][1], bh, zb); }
            else        { za = MFMA_16(a1[kt][0], bh, za); za = MFMA_16(a1[kt][0], bl, za); za = MFMA_16(a1[kt][1], bh, za); }
        }
        f32x4 zz = za + zb;
        union { unsigned long long u; _Float16 hh[4]; } ph, pl;
        #pragma unroll
        for (int r = 0; r < 4; ++r) {
            float v = zz[r];
            _Float16 hi = (_Float16)v;
            ph.hh[r] = hi; pl.hh[r] = (_Float16)(v - (float)hi);
        }
        *(unsigned long long*)&Zsp[((0*3 + Mt1) << 9) + zofs] = ph.u;
        *(unsigned long long*)&Zsp[((1*3 + Mt1) << 9) + zofs] = pl.u;
    };
    auto G2epi = [&](float beta) {
        #pragma unroll
        for (int r = 0; r < 16; ++r) acc[r] = 0.f;
        #pragma unroll
        for (int kt = 0; kt < 3; ++kt) {
            half8 bh = *(const half8*)&Zsp[((0*3 + kt) << 9) + (l << 3)];
            half8 bl = *(const half8*)&Zsp[((1*3 + kt) << 9) + (l << 3)];
            acc = MFMA_32(a2[kt][0], bh, acc);
            acc = MFMA_32(a2[kt][0], bl, acc);
            acc = MFMA_32(a2[kt][1], bh, acc);
        }
        #pragma unroll
        for (int gq = 0; gq < 4; ++gq) {
            union { unsigned long long u; _Float16 hh[4]; } yh, yl;
            #pragma unroll
            for (int j = 0; j < 4; ++j) {
                float ay = fmaf(-linv, acc[gq*4 + j], yo[gq][j]);
                float xn = fmaxf(0.f, ay + cm[gq][j]) + fminf(0.f, ay + cp[gq][j]);
                float yn = fmaf(beta, xn - xo[gq][j], xn);
                xo[gq][j] = xn; yo[gq][j] = yn;
                _Float16 hi = (_Float16)yn;
                yh.hh[j] = hi; yl.hh[j] = (_Float16)(yn - (float)hi);
            }
            int yofs = ((gq*16 + cl) << 3) + (s5 << 2);
            *(unsigned long long*)&Ysp[(((0*2 + nt16)*6 + Mt2) << 9) + yofs] = yh.u;
            *(unsigned long long*)&Ysp[(((1*2 + nt16)*6 + Mt2) << 9) + yofs] = yl.u;
        }
    };

    // ---- pipeline prologue: sub1 computes its first z (half-step offset)
    if (p == 1) G1body();
    __syncthreads();

    // ---- main loop: per half-step one sub runs G1, the other G2+epi
    float t_old = 0.5f * (1.f + sqrtf(5.f));
    for (int it = 1; it < NITER; ++it) {
        float t_new = 0.5f * (1.f + sqrtf(1.f + 4.f*t_old*t_old));
        float beta = (t_old - 1.f) / t_new;
        t_old = t_new;
        if (p == 0) G1body(); else G2epi(beta);
        __syncthreads();
        if (p == 0) G2epi(beta); else G1body();
        __syncthreads();
    }

    // ---- store final code
    #pragma unroll
    for (int gq = 0; gq < 4; ++gq) {
        int k0 = Mt2*32 + 8*gq + 4*s5;
        #pragma unroll
        for (int j = 0; j < 4; ++j) {
            int k = k0 + j;
            if (k < KK && fcol < FF)
                out[(size_t)n*KK*FF + k*FF + fcol] = xo[gq][j];
        }
    }

    if (!phase) {
        // ---- fused wnorm
        float s = 0.f;
        #pragma unroll
        for (int gq = 0; gq < 4; ++gq) {
            int k0 = Mt2*32 + 8*gq + 4*s5;
            #pragma unroll
            for (int j = 0; j < 4; ++j) {
                if (k0 + j < KK && fcol < FF) {
                    float wn = 1.f / (fabsf(xo[gq][j]) + 0.01f);
                    s += wn * wn;
                }
            }
        }
        #pragma unroll
        for (int off = 32; off > 0; off >>= 1) s += __shfl_down(s, off);
        float* red = (float*)Zs;
        if (l == 0) red[w] = s;
        __syncthreads();
        if (tid == 0) {
            float t = 0.f;
            #pragma unroll
            for (int i = 0; i < 12; ++i) t += red[i];
            atomicAdd(&ws[1], t);
        }
    } else {
        // ---- fused reconst: write x into own Ys image, GEMM1 pass, store
        #pragma unroll
        for (int gq = 0; gq < 4; ++gq) {
            union { unsigned long long u; _Float16 hh[4]; } yh, yl;
            #pragma unroll
            for (int j = 0; j < 4; ++j) {
                float v = xo[gq][j];
                _Float16 hi = (_Float16)v;
                yh.hh[j] = hi; yl.hh[j] = (_Float16)(v - (float)hi);
            }
            int yofs = ((gq*16 + cl) << 3) + (s5 << 2);
            *(unsigned long long*)&Ysp[(((0*2 + nt16)*6 + Mt2) << 9) + yofs] = yh.u;
            *(unsigned long long*)&Ysp[(((1*2 + nt16)*6 + Mt2) << 9) + yofs] = yl.u;
        }
        __syncthreads();
        f32x4 za = {0.f,0.f,0.f,0.f}, zb = {0.f,0.f,0.f,0.f};
        #pragma unroll
        for (int kt = 0; kt < 6; ++kt) {
            half8 bh = *(const half8*)&Ysp[(((0*2 + nt1)*6 + kt) << 9) + (l << 3)];
            half8 bl = *(const half8*)&Ysp[(((1*2 + nt1)*6 + kt) << 9) + (l << 3)];
            if (kt & 1) { zb = MFMA_16(a1[kt][0], bh, zb); zb = MFMA_16(a1[kt][0], bl, zb); zb = MFMA_16(a1[kt][1], bh, zb); }
            else        { za = MFMA_16(a1[kt][0], bh, za); za = MFMA_16(a1[kt][0], bl, za); za = MFMA_16(a1[kt][1], bh, za); }
        }
        f32x4 zz = za + zb;
        int fcol2 = p*32 + nt1*16 + cl;
        #pragma unroll
        for (int r = 0; r < 4; ++r) {
            int t = Mt1*16 + q*4 + r;
            if (t < TT && fcol2 < FF)
                out[R_OFF + (size_t)n*TT*FF + t*FF + fcol2] = zz[r];
        }
    }
}

// ---------------------------------------------------------------------------
extern "C" void kernel_launch(void* const* d_in, const int* in_sizes, int n_in,
                              void* d_out, int out_size, void* d_ws, size_t ws_size,
                              hipStream_t stream) {
    const float* x  = (const float*)d_in[0];
    const float* rr = (const float*)d_in[1];
    const float* th = (const float*)d_in[2];
    float* out = (float*)d_out;
    float* ws  = (float*)d_ws;

    hipLaunchKernelGGL(k_build, dim3(64),  dim3(256), 0, stream, rr, th, out, ws);
    hipLaunchKernelGGL(k_fista, dim3(NB),  dim3(768), 0, stream, ws, x, out, 0);
    hipLaunchKernelGGL(k_fista, dim3(NB),  dim3(768), 0, stream, ws, x, out, 1);
}

// Round 6
// 442.836 us; speedup vs baseline: 1.5407x; 1.4359x over previous
//
#include <hip/hip_runtime.h>
#include <math.h>

// Problem constants
#define NB   256
#define TT   36
#define FF   50
#define PP   80
#define KK   161
#define NITER 100
#define LAMB 0.1f

#define CODE_SZ (NB*KK*FF)          // 2,060,800
#define D_OFF   CODE_SZ
#define R_OFF   (CODE_SZ + TT*KK)

// ws float layout:
// [1] = wn^2 accumulator; [16..79] = ssq partials (64 k_build blocks)
// [WSA1..] A1 image (D):   [Mt1:3][kt:6][h:2][512] f16 = 9216 floats
// [WSA2..] A2 image (D^T): [Mt2:6][kt:3][h:2][512] f16 = 9216 floats
#define WSA1 128
#define WSA2 (128 + 9216)

typedef _Float16 half8 __attribute__((ext_vector_type(8)));
typedef float f32x4  __attribute__((ext_vector_type(4)));
typedef float f32x16 __attribute__((ext_vector_type(16)));
#define MFMA_16(A,B,C) __builtin_amdgcn_mfma_f32_16x16x32_f16(A,B,C,0,0,0)
#define MFMA_32(A,B,C) __builtin_amdgcn_mfma_f32_32x32x16_f16(A,B,C,0,0,0)

// ---------------------------------------------------------------------------
// K1 (grid 64): build D (blk0 -> d_out), ssq partials -> ws[16+b], pack f16
// hi/lo MFMA A-operand images for D (GEMM1 16x16x32) and D^T (GEMM2 32x32x16).
__global__ __launch_bounds__(256) void k_build(const float* __restrict__ rr,
                                               const float* __restrict__ th,
                                               float* __restrict__ out,
                                               float* __restrict__ ws) {
    __shared__ float Dl[TT*KK];
    __shared__ float red[256];
    int tid = threadIdx.x, b = blockIdx.x;
    for (int e = tid; e < TT*KK; e += 256) {
        int t = e / KK, k = e % KK;
        float v;
        if (k == 0) v = 1.f;
        else if (k <= PP) { int p = k - 1;     v = powf(rr[p], (float)t) * cosf((float)t * th[p]); }
        else              { int p = k - 1 - PP; v = powf(rr[p], (float)t) * sinf((float)t * th[p]); }
        Dl[e] = v;
        if (b == 0) out[D_OFF + e] = v;
    }
    __syncthreads();
    float ssq = 0.f;
    for (int p = b*256 + tid; p < KK*KK; p += 64*256) {
        int k1 = p / KK, k2 = p % KK;
        float s = 0.f;
        for (int t = 0; t < TT; ++t) s += Dl[t*KK + k1] * Dl[t*KK + k2];
        ssq += s * s;
    }
    red[tid] = ssq;
    __syncthreads();
    for (int off = 128; off > 0; off >>= 1) {
        if (tid < off) red[tid] += red[tid + off];
        __syncthreads();
    }
    if (tid == 0) { ws[16 + b] = red[0]; if (b == 0) ws[1] = 0.f; }

    // A1: lane l holds A[m=l&15][k=8*(l>>4)+i] per 16x16x32 tile
    _Float16* a1 = (_Float16*)(ws + WSA1);
    for (int e = b*256 + tid; e < 3*6*2*512; e += 64*256) {
        int fp = e & 511, r = e >> 9;       // r = (Mt1*6+kt)*2 + h
        int h = r & 1, mk = r >> 1;
        int l = fp >> 3, i = fp & 7;
        int t = (mk / 6) * 16 + (l & 15);
        int j = (mk % 6) * 32 + ((l >> 4) << 3) + i;
        float v = (t < TT && j < KK) ? Dl[t*KK + j] : 0.f;
        _Float16 hi = (_Float16)v;
        a1[e] = h ? (_Float16)(v - (float)hi) : hi;
    }
    // A2 (D^T): lane l holds A[m=l&31][k=8*(l>>5)+i] per 32x32x16 tile
    _Float16* a2 = (_Float16*)(ws + WSA2);
    for (int e = b*256 + tid; e < 6*3*2*512; e += 64*256) {
        int fp = e & 511, r = e >> 9;       // r = (Mt2*3+kt)*2 + h
        int h = r & 1, mk = r >> 1;
        int l = fp >> 3, i = fp & 7;
        int m = (mk / 3) * 32 + (l & 31);
        int t = (mk % 3) * 16 + ((l >> 5) << 3) + i;
        float v = (m < KK && t < TT) ? Dl[t*KK + m] : 0.f;
        _Float16 hi = (_Float16)v;
        a2[e] = h ? (_Float16)(v - (float)hi) : hi;
    }
}

// ---------------------------------------------------------------------------
// K2: fused FISTA, grid 256 (one n per block), 768 threads = 12 waves, all
// waves cooperate on one 64-col problem (R3 structure). 2-term quantized
// GEMMs: y,z stored f16-hi only in LDS; D kept hi+lo in registers, so each
// GEMM computes D x f16(operand) at ~fp32 accuracy.
// GEMM1 (z = D y): 16x16x32, wave = (Mt1 = w>>2, nt1 = w&3).
// GEMM2 (w = D^T z): 32x32x16, wave = (Mt2 = w>>1, nh = w&1).
// Head: DtY via GEMM2 over f16(x). Tails: ph0 wnorm, ph1 reconst.
__global__ __launch_bounds__(768, 3) void k_fista(float* __restrict__ ws,
                                                  const float* __restrict__ x,
                                                  float* __restrict__ out,
                                                  int phase) {
    __shared__ _Float16 Ys[4*6*512];   // 24,576 B: [nt16:4][kt32:6][512]
    __shared__ _Float16 Zs[2*3*512];   //  6,144 B: [nh:2][kt16:3][512]
    int tid = threadIdx.x;
    int w = tid >> 6, l = tid & 63;
    int n = blockIdx.x;

    // ---- stage x -> Zs (f16 hi, GEMM2 B-frag image, k-dim = t)
    const float* xb = x + n*TT*FF;
    for (int e = tid; e < 3072; e += 768) {
        int t = e >> 6, c64 = e & 63;
        float v = (t < TT && c64 < FF) ? xb[t*FF + c64] : 0.f;
        int nh = c64 >> 5, c = c64 & 31;
        int kt = t >> 4, kk = t & 15;
        int ofs = ((((kk >> 3) << 5) + c) << 3) + (kk & 7);
        Zs[((nh*3 + kt) << 9) + ofs] = (_Float16)v;
    }

    float ssum = 0.f;
    #pragma unroll
    for (int i = 0; i < 64; ++i) ssum += ws[16 + i];
    float linv = rsqrtf(ssum);

    int Mt1 = w >> 2, nt1 = w & 3;     // GEMM1 role
    int Mt2 = w >> 1, nh  = w & 1;     // GEMM2 role
    const _Float16* a1g = (const _Float16*)(ws + WSA1);
    const _Float16* a2g = (const _Float16*)(ws + WSA2);
    half8 a1[6][2], a2[3][2];
    #pragma unroll
    for (int kt = 0; kt < 6; ++kt)
        #pragma unroll
        for (int h = 0; h < 2; ++h)
            a1[kt][h] = *(const half8*)(a1g + ((((Mt1*6 + kt)*2 + h) << 9) + (l << 3)));
    #pragma unroll
    for (int kt = 0; kt < 3; ++kt)
        #pragma unroll
        for (int h = 0; h < 2; ++h)
            a2[kt][h] = *(const half8*)(a2g + ((((Mt2*3 + kt)*2 + h) << 9) + (l << 3)));
    __syncthreads();

    // ---- head GEMM2: acc = D^T @ f16(x)  (c-vector, registers only)
    f32x16 acc;
    #pragma unroll
    for (int r = 0; r < 16; ++r) acc[r] = 0.f;
    #pragma unroll
    for (int kt = 0; kt < 3; ++kt) {
        half8 bh = *(const half8*)&Zs[((nh*3 + kt) << 9) + (l << 3)];
        acc = MFMA_32(a2[kt][0], bh, acc);
        acc = MFMA_32(a2[kt][1], bh, acc);
    }

    int cl = l & 15, q = l >> 4;       // GEMM1 C addressing
    int nloc = l & 31, s5 = l >> 5;    // GEMM2 C addressing
    int nt16 = nh*2 + (nloc >> 4);
    int fcol = nh*32 + nloc;           // global f of owned columns
    int zofs = ((((q >> 1) << 5) + (nt1 & 1)*16 + cl) << 3) + ((q & 1) << 2);
    int znh = nt1 >> 1;
    float cm[4][4], cp[4][4], xo[4][4], yo[4][4];

    // ---- peeled iteration 0: x1 = shrink(c), y1 = x1
    {
        float wl0 = LAMB * linv;
        float fac = 0.f;
        if (phase) fac = (float)KK * LAMB * linv * rsqrtf(ws[1]);
        #pragma unroll
        for (int gq = 0; gq < 4; ++gq) {
            int k0 = Mt2*32 + 8*gq + 4*s5;
            union { unsigned long long u; _Float16 hh[4]; } yh;
            #pragma unroll
            for (int j = 0; j < 4; ++j) {
                int k = k0 + j;
                float cv = 0.f, wl = 0.f;
                if (k < KK && fcol < FF) {
                    cv = linv * acc[gq*4 + j];
                    if (phase) {
                        float prev = out[(size_t)n*KK*FF + k*FF + fcol];
                        wl = fac / (fabsf(prev) + 0.01f);
                    } else wl = wl0;
                }
                cm[gq][j] = cv - wl; cp[gq][j] = cv + wl;
                float xn = fmaxf(0.f, cm[gq][j]) + fminf(0.f, cp[gq][j]);
                xo[gq][j] = xn; yo[gq][j] = xn;
                yh.hh[j] = (_Float16)xn;
            }
            int yofs = ((gq*16 + cl) << 3) + (s5 << 2);
            *(unsigned long long*)&Ys[((nt16*6 + Mt2) << 9) + yofs] = yh.u;
        }
    }
    __syncthreads();

    float t_old = 0.5f * (1.f + sqrtf(5.f));
    for (int it = 1; it < NITER; ++it) {
        // ---- GEMM1: z(Mt1, nt1) = D @ f16(y)  (2 chains: hi, lo of D)
        f32x4 za = {0.f,0.f,0.f,0.f}, zb = {0.f,0.f,0.f,0.f};
        #pragma unroll
        for (int kt = 0; kt < 6; ++kt) {
            half8 bh = *(const half8*)&Ys[((nt1*6 + kt) << 9) + (l << 3)];
            za = MFMA_16(a1[kt][0], bh, za);
            zb = MFMA_16(a1[kt][1], bh, zb);
        }
        f32x4 zz = za + zb;
        {
            union { unsigned long long u; _Float16 hh[4]; } ph;
            #pragma unroll
            for (int r = 0; r < 4; ++r) ph.hh[r] = (_Float16)zz[r];
            *(unsigned long long*)&Zs[((znh*3 + Mt1) << 9) + zofs] = ph.u;
        }
        __syncthreads();

        // ---- GEMM2: acc(Mt2, nh) = D^T @ f16(z)
        #pragma unroll
        for (int r = 0; r < 16; ++r) acc[r] = 0.f;
        #pragma unroll
        for (int kt = 0; kt < 3; ++kt) {
            half8 bh = *(const half8*)&Zs[((nh*3 + kt) << 9) + (l << 3)];
            acc = MFMA_32(a2[kt][0], bh, acc);
            acc = MFMA_32(a2[kt][1], bh, acc);
        }
        // ---- epilogue: shrink + momentum, rebuild y image (f16 hi)
        float t_new = 0.5f * (1.f + sqrtf(1.f + 4.f*t_old*t_old));
        float beta = (t_old - 1.f) / t_new;
        t_old = t_new;
        #pragma unroll
        for (int gq = 0; gq < 4; ++gq) {
            union { unsigned long long u; _Float16 hh[4]; } yh;
            #pragma unroll
            for (int j = 0; j < 4; ++j) {
                float ay = fmaf(-linv, acc[gq*4 + j], yo[gq][j]);
                float xn = fmaxf(0.f, ay + cm[gq][j]) + fminf(0.f, ay + cp[gq][j]);
                float yn = fmaf(beta, xn - xo[gq][j], xn);
                xo[gq][j] = xn; yo[gq][j] = yn;
                yh.hh[j] = (_Float16)yn;
            }
            int yofs = ((gq*16 + cl) << 3) + (s5 << 2);
            *(unsigned long long*)&Ys[((nt16*6 + Mt2) << 9) + yofs] = yh.u;
        }
        __syncthreads();
    }

    // ---- store final code
    #pragma unroll
    for (int gq = 0; gq < 4; ++gq) {
        int k0 = Mt2*32 + 8*gq + 4*s5;
        #pragma unroll
        for (int j = 0; j < 4; ++j) {
            int k = k0 + j;
            if (k < KK && fcol < FF)
                out[(size_t)n*KK*FF + k*FF + fcol] = xo[gq][j];
        }
    }

    if (!phase) {
        // ---- fused wnorm
        float s = 0.f;
        #pragma unroll
        for (int gq = 0; gq < 4; ++gq) {
            int k0 = Mt2*32 + 8*gq + 4*s5;
            #pragma unroll
            for (int j = 0; j < 4; ++j) {
                if (k0 + j < KK && fcol < FF) {
                    float wn = 1.f / (fabsf(xo[gq][j]) + 0.01f);
                    s += wn * wn;
                }
            }
        }
        #pragma unroll
        for (int off = 32; off > 0; off >>= 1) s += __shfl_down(s, off);
        float* red = (float*)Zs;
        if (l == 0) red[w] = s;
        __syncthreads();
        if (tid == 0) {
            float t = 0.f;
            #pragma unroll
            for (int i = 0; i < 12; ++i) t += red[i];
            atomicAdd(&ws[1], t);
        }
    } else {
        // ---- fused reconst: f16(code) into Ys, GEMM1 pass, store
        #pragma unroll
        for (int gq = 0; gq < 4; ++gq) {
            union { unsigned long long u; _Float16 hh[4]; } yh;
            #pragma unroll
            for (int j = 0; j < 4; ++j) yh.hh[j] = (_Float16)xo[gq][j];
            int yofs = ((gq*16 + cl) << 3) + (s5 << 2);
            *(unsigned long long*)&Ys[((nt16*6 + Mt2) << 9) + yofs] = yh.u;
        }
        __syncthreads();
        f32x4 za = {0.f,0.f,0.f,0.f}, zb = {0.f,0.f,0.f,0.f};
        #pragma unroll
        for (int kt = 0; kt < 6; ++kt) {
            half8 bh = *(const half8*)&Ys[((nt1*6 + kt) << 9) + (l << 3)];
            za = MFMA_16(a1[kt][0], bh, za);
            zb = MFMA_16(a1[kt][1], bh, zb);
        }
        f32x4 zz = za + zb;
        int fcol2 = nt1*16 + cl;
        #pragma unroll
        for (int r = 0; r < 4; ++r) {
            int t = Mt1*16 + q*4 + r;
            if (t < TT && fcol2 < FF)
                out[R_OFF + (size_t)n*TT*FF + t*FF + fcol2] = zz[r];
        }
    }
}

// ---------------------------------------------------------------------------
extern "C" void kernel_launch(void* const* d_in, const int* in_sizes, int n_in,
                              void* d_out, int out_size, void* d_ws, size_t ws_size,
                              hipStream_t stream) {
    const float* x  = (const float*)d_in[0];
    const float* rr = (const float*)d_in[1];
    const float* th = (const float*)d_in[2];
    float* out = (float*)d_out;
    float* ws  = (float*)d_ws;

    hipLaunchKernelGGL(k_build, dim3(64),  dim3(256), 0, stream, rr, th, out, ws);
    hipLaunchKernelGGL(k_fista, dim3(NB),  dim3(768), 0, stream, ws, x, out, 0);
    hipLaunchKernelGGL(k_fista, dim3(NB),  dim3(768), 0, stream, ws, x, out, 1);
}